// Round 10
// baseline (1468.019 us; speedup 1.0000x reference)
//
#include <hip/hip_runtime.h>
#include <math.h>

#define H 512
#define V 5000
#define BB 128
#define SS 64
#define TT 52
#define NB 160   // persistent grid size

typedef __attribute__((ext_vector_type(8))) short bf16x8;
typedef __attribute__((ext_vector_type(4))) float f32x4;
typedef __attribute__((ext_vector_type(2))) float f32x2;

__device__ __forceinline__ unsigned short f2b(float f) {
    unsigned u = __float_as_uint(f);
    return (unsigned short)((u + 0x7fffu + ((u >> 16) & 1u)) >> 16);
}
__device__ __forceinline__ float b2f(unsigned short u) {
    return __uint_as_float((unsigned)u << 16);
}
__device__ __forceinline__ float ftanh(float x) {
    return 1.f - 2.f / (1.f + __expf(2.f * x));
}
__device__ __forceinline__ float fsig(float x) {
    return 1.f / (1.f + __expf(-x));
}
__device__ __forceinline__ unsigned char f2fp8(float f) {
    return (unsigned char)__builtin_amdgcn_cvt_pk_fp8_f32(f, f, 0, 0);
}

// ---------------------------------------------------------------------------
// Coherent (L1/L2-bypassing, L3-coherence-point) accesses; validated r4-r9.
// ---------------------------------------------------------------------------
#define CLD16_BODY \
        "global_load_dwordx4 %0, %16, off sc0 sc1\n\t"              \
        "global_load_dwordx4 %1, %16, off offset:64 sc0 sc1\n\t"    \
        "global_load_dwordx4 %2, %16, off offset:128 sc0 sc1\n\t"   \
        "global_load_dwordx4 %3, %16, off offset:192 sc0 sc1\n\t"   \
        "global_load_dwordx4 %4, %16, off offset:256 sc0 sc1\n\t"   \
        "global_load_dwordx4 %5, %16, off offset:320 sc0 sc1\n\t"   \
        "global_load_dwordx4 %6, %16, off offset:384 sc0 sc1\n\t"   \
        "global_load_dwordx4 %7, %16, off offset:448 sc0 sc1\n\t"   \
        "global_load_dwordx4 %8, %16, off offset:512 sc0 sc1\n\t"   \
        "global_load_dwordx4 %9, %16, off offset:576 sc0 sc1\n\t"   \
        "global_load_dwordx4 %10, %16, off offset:640 sc0 sc1\n\t"  \
        "global_load_dwordx4 %11, %16, off offset:704 sc0 sc1\n\t"  \
        "global_load_dwordx4 %12, %16, off offset:768 sc0 sc1\n\t"  \
        "global_load_dwordx4 %13, %16, off offset:832 sc0 sc1\n\t"  \
        "global_load_dwordx4 %14, %16, off offset:896 sc0 sc1\n\t"  \
        "global_load_dwordx4 %15, %16, off offset:960 sc0 sc1"
#define CLD16_OUTS(r) \
          "=v"(r[0]), "=v"(r[1]), "=v"(r[2]), "=v"(r[3]),   \
          "=v"(r[4]), "=v"(r[5]), "=v"(r[6]), "=v"(r[7]),   \
          "=v"(r[8]), "=v"(r[9]), "=v"(r[10]), "=v"(r[11]), \
          "=v"(r[12]), "=v"(r[13]), "=v"(r[14]), "=v"(r[15])

__device__ __forceinline__ void cld_row16_nw(const unsigned short* p, bf16x8* r)
{
    asm volatile(CLD16_BODY : CLD16_OUTS(r) : "v"(p) : "memory");
}
__device__ __forceinline__ void cld_row16(const unsigned short* p, bf16x8* r)
{
    asm volatile(CLD16_BODY "\n\ts_waitcnt vmcnt(0)"
                 : CLD16_OUTS(r) : "v"(p) : "memory");
}
__device__ __forceinline__ void cld_f_2(const float* p0, const float* p1,
                                        float& a, float& b)
{
    asm volatile(
        "global_load_dword %0, %2, off sc0 sc1\n\t"
        "global_load_dword %1, %3, off sc0 sc1\n\t"
        "s_waitcnt vmcnt(0)"
        : "=v"(a), "=v"(b) : "v"(p0), "v"(p1) : "memory");
}
__device__ __forceinline__ void cld_f4p(const float* p, f32x4& a, f32x4& b)
{
    asm volatile(
        "global_load_dwordx4 %0, %2, off sc0 sc1\n\t"
        "global_load_dwordx4 %1, %2, off offset:16 sc0 sc1\n\t"
        "s_waitcnt vmcnt(0)"
        : "=v"(a), "=v"(b) : "v"(p) : "memory");
}
__device__ __forceinline__ void cst_f(float* p, float v)
{
    asm volatile("global_store_dword %0, %1, off sc0 sc1"
                 :: "v"(p), "v"(v) : "memory");
}
__device__ __forceinline__ void cst_u32(unsigned* p, unsigned v)
{
    asm volatile("global_store_dword %0, %1, off sc0 sc1"
                 :: "v"(p), "v"(v) : "memory");
}
__device__ __forceinline__ void cst_h(unsigned short* p, unsigned short v)
{
    unsigned vv = v;
    asm volatile("global_store_short %0, %1, off sc0 sc1"
                 :: "v"(p), "v"(vv) : "memory");
}

// ---------------------------------------------------------------------------
// prep kernels (unchanged)
// ---------------------------------------------------------------------------
__global__ __launch_bounds__(256)
void prep_w(const float* __restrict__ Wa, const float* __restrict__ Whh,
            const float* __restrict__ Wih,
            const float* __restrict__ ba, const float* __restrict__ bih,
            const float* __restrict__ bhh,
            const float* __restrict__ Ua, const float* __restrict__ Wout,
            const float* __restrict__ enc,
            unsigned short* __restrict__ Wbig, unsigned short* __restrict__ Wc,
            unsigned short* __restrict__ Uab, unsigned short* __restrict__ Woutb,
            unsigned short* __restrict__ encb, float* __restrict__ bbig)
{
    const int stride = gridDim.x * blockDim.x;
    const int t0 = blockIdx.x * blockDim.x + threadIdx.x;
    for (int idx = t0; idx < 2560 * 1024; idx += stride) {
        const int j = idx >> 10, k = idx & 1023;
        float v;
        if (j < H) v = (k < H) ? Wa[j * H + k] : 0.f;
        else { const int n = j - H; v = (k < H) ? Whh[n * H + k] : Wih[n * 2 * H + (k - H)]; }
        Wbig[idx] = f2b(v);
    }
    for (int idx = t0; idx < 2048 * 512; idx += stride) {
        const int n = idx >> 9, k = idx & 511;
        Wc[idx] = f2b(Wih[n * 2 * H + H + k]);
    }
    for (int idx = t0; idx < 512 * 512; idx += stride)   Uab[idx]   = f2b(Ua[idx]);
    for (int idx = t0; idx < V * 512; idx += stride)     Woutb[idx] = f2b(Wout[idx]);
    for (int idx = t0; idx < BB * SS * H; idx += stride) encb[idx]  = f2b(enc[idx]);
    for (int j = t0; j < 2560; j += stride)
        bbig[j] = (j < H) ? ba[j] : bih[j - H] + bhh[j - H];
}

__global__ __launch_bounds__(256)
void gather_x(const float* __restrict__ emb, const int* __restrict__ tgt,
              unsigned short* __restrict__ xall)
{
    const int stride = gridDim.x * blockDim.x;
    for (int idx = blockIdx.x * blockDim.x + threadIdx.x; idx < TT * BB * H; idx += stride) {
        const int k = idx & 511;
        const int row = idx >> 9;
        const int t = row >> 7, b = row & 127;
        const int tok = (t == 0) ? 0 : tgt[b * TT + t - 1];
        xall[idx] = f2b(emb[(size_t)tok * H + k]);
    }
}

// ---------------------------------------------------------------------------
// bf16 MFMA NT-GEMM, K=512 fixed (unchanged).
// ---------------------------------------------------------------------------
template<int OUT_MODE, int PERMUTE>
__global__ __launch_bounds__(256, 2)
void gemm_mfma(const unsigned short* __restrict__ A,
               const unsigned short* __restrict__ B,
               const float* __restrict__ bias,
               float* __restrict__ Cf, unsigned short* __restrict__ Cb,
               unsigned char* __restrict__ C8,
               int M, int N)
{
    __shared__ unsigned short As[128][72];
    __shared__ unsigned short Bs[128][72];
    const int tid = threadIdx.x;
    const int m0 = blockIdx.y * 128, n0 = blockIdx.x * 128;
    const int lane = tid & 63, wv = tid >> 6;
    const int qm = (wv >> 1) * 64, qn = (wv & 1) * 64;
    const int fr = lane & 15, fg = lane >> 4;
    f32x4 acc[4][4];
#pragma unroll
    for (int i = 0; i < 4; ++i)
#pragma unroll
        for (int j = 0; j < 4; ++j) acc[i][j] = (f32x4){0.f, 0.f, 0.f, 0.f};

    const int srow = tid >> 3, sc = (tid & 7) * 8;
    for (int k0 = 0; k0 < H; k0 += 64) {
#pragma unroll
        for (int u = 0; u < 4; ++u) {
            const int row = srow + u * 32;
            *(uint4*)&As[row][sc] = *(const uint4*)&A[(size_t)(m0 + row) * H + k0 + sc];
            int nr = n0 + row; if (nr > N - 1) nr = N - 1;
            *(uint4*)&Bs[row][sc] = *(const uint4*)&B[(size_t)nr * H + k0 + sc];
        }
        __syncthreads();
#pragma unroll
        for (int ks = 0; ks < 2; ++ks) {
            const int kk = ks * 32 + fg * 8;
            bf16x8 av[4], bv[4];
#pragma unroll
            for (int i = 0; i < 4; ++i) {
                av[i] = *(const bf16x8*)&As[qm + i * 16 + fr][kk];
                bv[i] = *(const bf16x8*)&Bs[qn + i * 16 + fr][kk];
            }
#pragma unroll
            for (int i = 0; i < 4; ++i)
#pragma unroll
                for (int j = 0; j < 4; ++j)
                    acc[i][j] = __builtin_amdgcn_mfma_f32_16x16x32_bf16(av[i], bv[j], acc[i][j], 0, 0, 0);
        }
        __syncthreads();
    }
#pragma unroll
    for (int i = 0; i < 4; ++i) {
        const int r0 = m0 + qm + i * 16 + fg * 4;
#pragma unroll
        for (int j = 0; j < 4; ++j) {
            const int col = n0 + qn + j * 16 + fr;
            if (col < N) {
                const float bi = bias ? bias[col] : 0.f;
#pragma unroll
                for (int v = 0; v < 4; ++v) {
                    const int r = r0 + v;
                    const float val = acc[i][j][v] + bi;
                    if (OUT_MODE == 1) {
                        Cb[(size_t)r * N + col] = f2b(val);
                    } else if (OUT_MODE == 2) {
                        C8[(size_t)r * N + col] = f2fp8(val);
                    } else {
                        const size_t orow = PERMUTE ? ((size_t)(r & (BB - 1)) * TT + (r >> 7))
                                                    : (size_t)r;
                        Cf[orow * (size_t)N + col] = val;
                    }
                }
            }
        }
    }
}

// ---------------------------------------------------------------------------
// Mailbox flags (v7). Each class replicated x8: consumer polls replica
// (blockIdx&7) only -> ~16-20 pollers/line instead of 128-160 (the L3
// poll-congestion fix). Producers write all 8 replicas (pipelined stores).
// Backoff s_sleep(2) cuts poll rate further. All relaxed; data ordering via
// sc0sc1 write-through + __syncthreads drain before signal (validated r4-r9).
// ---------------------------------------------------------------------------
__device__ __forceinline__ void poll_ge(unsigned* a, unsigned step)
{
    if (__hip_atomic_load(a, __ATOMIC_RELAXED, __HIP_MEMORY_SCOPE_AGENT) >= step)
        return;
    do {
        __builtin_amdgcn_s_sleep(2);
    } while (__hip_atomic_load(a, __ATOMIC_RELAXED, __HIP_MEMORY_SCOPE_AGENT) < step);
}

struct PParams {
    const float* h0;
    const float* c0;
    const unsigned short* keysb;  // [B*S][512] bf16 (read-only, L2-cached)
    const unsigned char* encW8;   // [B*S][2048] fp8 (read-only, L2-resident)
    const float* Va;
    const float* bv;
    const float* bbig;
    const unsigned short* Wbig;   // [2560][1024] bf16
    const unsigned short* xall;   // [T*B][512]   bf16 (read-only)
    unsigned short* hbf;          // [B][512] bf16   -- coherent (cross-block)
    float* Y;                     // [B][2560] f32   -- coherent (cross-block)
    unsigned short* hallb;        // [T*B][512] bf16 (consumed post-kernel)
    float* attn;                  // -> d_out attention block [B][T][S]
    float* out_h;
    float* out_c;
    unsigned* pflag;              // [160]      prologue, no replicas
    unsigned* qaflag;             // [8][32]    qa producers (blocks 128-159)
    unsigned* gateflag;           // [8][128]   gate producers (blocks 0-127)
    unsigned* hflag;              // [8][128]   h producers (P2 blocks)
};

// ---------------------------------------------------------------------------
// Persistent recurrence kernel (160 blocks). Same dataflow as round 9
// (remapped columns, per-wave h gating, split qa/gate waits), new mailbox
// signal/wait plumbing. Flag values are step counters (t+1).
// ---------------------------------------------------------------------------
__global__ __launch_bounds__(256, 1)
void persist(PParams p)
{
    __shared__ unsigned short WA[16][1032];
    __shared__ float qa_s[H];
    __shared__ float va_s[H];
    __shared__ float part[SS][4];
    __shared__ float wbuf[SS];
    __shared__ float gbuf[4 * H];
    __shared__ float cs[H];

    const int tid  = threadIdx.x;
    const int beta = blockIdx.x;
    const int rep  = beta & 7;
    const int j0   = (beta < 128) ? (512 + beta * 16) : ((beta - 128) * 16);

    // ---- prologue: h0 -> bf16 (coherent), stage weight slice, init c ----
    for (int i = beta * 256 + tid; i < BB * H; i += NB * 256)
        cst_h(&p.hbf[i], f2b(p.h0[i]));
    for (int idx = tid; idx < 16 * 128; idx += 256) {
        const int r = idx >> 7, ch = idx & 127;
        *(uint4*)&WA[r][ch * 8] = *(const uint4*)&p.Wbig[(size_t)(j0 + r) * 1024 + ch * 8];
    }
    if (beta < 128) {
        for (int j = tid; j < H; j += 256) cs[j] = p.c0[beta * H + j];
        for (int i = tid; i < H; i += 256) va_s[i] = p.Va[i];
    }
    __syncthreads();
    if (tid == 0)
        __hip_atomic_store(&p.pflag[beta * 32], 1u, __ATOMIC_RELAXED,
                           __HIP_MEMORY_SCOPE_AGENT);
    for (int i = tid; i < NB; i += 256) poll_ge(&p.pflag[i * 32], 1u);
    __syncthreads();

    for (int t = 0; t < TT; ++t) {
        const unsigned st = (unsigned)(t + 1);
        // ---------------- P1: Y[b][j0..j0+15] for all b ----------------
        {
            const int wv = tid >> 6, lane = tid & 63;
            const int r = lane & 15, g = lane >> 4;
            const int b0 = wv * 32, b1 = b0 + 16;
            const int ko = g * 8;
            // gate only on MY wave's 32 h-producers (blocks b0..b0+31)
            if (t > 0 && lane < 32)
                poll_ge(&p.hflag[(rep * 128 + b0 + lane) * 32], (unsigned)t);
            bf16x8 hr0[16], hr1[16];
            cld_row16_nw(p.hbf + (size_t)(b0 + r) * H + ko, hr0);
            cld_row16  (p.hbf + (size_t)(b1 + r) * H + ko, hr1);
            __builtin_amdgcn_sched_barrier(0);   // MFMA hoist fence (rule #18)
            f32x4 acc0 = {0.f, 0.f, 0.f, 0.f};
            f32x4 acc1 = {0.f, 0.f, 0.f, 0.f};
#pragma unroll
            for (int ks = 0; ks < 16; ++ks) {
                bf16x8 bf = *(const bf16x8*)&WA[r][ks * 32 + ko];
                acc0 = __builtin_amdgcn_mfma_f32_16x16x32_bf16(hr0[ks], bf, acc0, 0, 0, 0);
                acc1 = __builtin_amdgcn_mfma_f32_16x16x32_bf16(hr1[ks], bf, acc1, 0, 0, 0);
            }
            const unsigned short* x0p = p.xall + ((size_t)t * BB + b0 + r) * H + ko;
            const unsigned short* x1p = p.xall + ((size_t)t * BB + b1 + r) * H + ko;
#pragma unroll
            for (int ks = 0; ks < 16; ++ks) {
                bf16x8 bf = *(const bf16x8*)&WA[r][512 + ks * 32 + ko];
                acc0 = __builtin_amdgcn_mfma_f32_16x16x32_bf16(*(const bf16x8*)&x0p[ks * 32], bf, acc0, 0, 0, 0);
                acc1 = __builtin_amdgcn_mfma_f32_16x16x32_bf16(*(const bf16x8*)&x1p[ks * 32], bf, acc1, 0, 0, 0);
            }
            const float bb = p.bbig[j0 + r];
#pragma unroll
            for (int i = 0; i < 4; ++i) {
                cst_f(p.Y + (size_t)(b0 + g * 4 + i) * 2560 + j0 + r, acc0[i] + bb);
                cst_f(p.Y + (size_t)(b1 + g * 4 + i) * 2560 + j0 + r, acc1[i] + bb);
            }
        }
        __syncthreads();   // drain all waves' Y stores
        if (tid < 8) {     // publish P1-done to all 8 replicas
            if (beta < 128)
                __hip_atomic_store(&p.gateflag[(tid * 128 + beta) * 32], st,
                                   __ATOMIC_RELAXED, __HIP_MEMORY_SCOPE_AGENT);
            else
                __hip_atomic_store(&p.qaflag[(tid * 32 + beta - 128) * 32], st,
                                   __ATOMIC_RELAXED, __HIP_MEMORY_SCOPE_AGENT);
        }

        // ------- P2: attention + ctx-gates + LSTM for batch b = beta -------
        if (beta < 128) {
            const int b = beta;
            const float* yrow = p.Y + (size_t)b * 2560;
            if (tid < 32) poll_ge(&p.qaflag[(rep * 32 + tid) * 32], st);
            __syncthreads();
            cld_f_2(yrow + tid, yrow + 256 + tid, qa_s[tid], qa_s[tid + 256]);
            __syncthreads();
            // scores: vectorized keysb (bf16x8), 2-way ILP tanh chain
            const int s = tid >> 2, q = tid & 3;
            const unsigned short* kp = p.keysb + ((size_t)b * SS + s) * H + q * 128;
            const float* qp = qa_s + q * 128;
            const float* vp = va_s + q * 128;
            float a2 = 0.f, a2b = 0.f;
#pragma unroll
            for (int i8 = 0; i8 < 16; ++i8) {
                bf16x8 kv = *(const bf16x8*)&kp[i8 * 8];
#pragma unroll
                for (int u = 0; u < 8; u += 2) {
                    const int i = i8 * 8 + u;
                    a2  += ftanh(qp[i]     + b2f((unsigned short)kv[u]))     * vp[i];
                    a2b += ftanh(qp[i + 1] + b2f((unsigned short)kv[u + 1])) * vp[i + 1];
                }
            }
            part[s][q] = a2 + a2b;
            __syncthreads();
            if (tid < 64) {
                float sc = part[tid][0] + part[tid][1] + part[tid][2] + part[tid][3] + p.bv[0];
                float m = sc;
                for (int o = 32; o; o >>= 1) m = fmaxf(m, __shfl_xor(m, o));
                const float e = __expf(sc - m);
                float ss = e;
                for (int o = 32; o; o >>= 1) ss += __shfl_xor(ss, o);
                const float w = e / ss;
                wbuf[tid] = w;
                p.attn[((size_t)b * TT + t) * SS + tid] = w;
            }
            if (tid < 128) poll_ge(&p.gateflag[(rep * 128 + tid) * 32], st);
            __syncthreads();
            // gates_ctx via fp8 encW weighted sum; 8 n per thread
            {
                float gc[8] = {0.f, 0.f, 0.f, 0.f, 0.f, 0.f, 0.f, 0.f};
                const unsigned char* ew = p.encW8 + (size_t)b * SS * 2048 + tid * 8;
#pragma unroll 8
                for (int s2 = 0; s2 < SS; ++s2) {
                    const float w2 = wbuf[s2];
                    const uint2 u = *(const uint2*)(ew + (size_t)s2 * 2048);
                    const f32x2 e01 = __builtin_amdgcn_cvt_pk_f32_fp8(u.x, 0);
                    const f32x2 e23 = __builtin_amdgcn_cvt_pk_f32_fp8(u.x, 1);
                    const f32x2 e45 = __builtin_amdgcn_cvt_pk_f32_fp8(u.y, 0);
                    const f32x2 e67 = __builtin_amdgcn_cvt_pk_f32_fp8(u.y, 1);
                    gc[0] += w2 * e01[0]; gc[1] += w2 * e01[1];
                    gc[2] += w2 * e23[0]; gc[3] += w2 * e23[1];
                    gc[4] += w2 * e45[0]; gc[5] += w2 * e45[1];
                    gc[6] += w2 * e67[0]; gc[7] += w2 * e67[1];
                }
                f32x4 y0, y1;
                cld_f4p(yrow + 512 + tid * 8, y0, y1);
#pragma unroll
                for (int i = 0; i < 4; ++i) {
                    gbuf[tid * 8 + i]     = gc[i] + y0[i];
                    gbuf[tid * 8 + 4 + i] = gc[4 + i] + y1[i];
                }
            }
            __syncthreads();
            // LSTM: cells 2*tid, 2*tid+1
            {
                const int last = (t == TT - 1);
                unsigned hpack = 0;
                float hn2[2], cn2[2];
#pragma unroll
                for (int u = 0; u < 2; ++u) {
                    const int j = tid * 2 + u;
                    const float ig = gbuf[j];
                    const float fg = gbuf[512 + j];
                    const float gg = gbuf[1024 + j];
                    const float og = gbuf[1536 + j];
                    const float co = cs[j];
                    const float cn = fsig(fg) * co + fsig(ig) * ftanh(gg);
                    const float hn = fsig(og) * ftanh(cn);
                    cs[j] = cn;
                    hn2[u] = hn; cn2[u] = cn;
                    hpack |= ((unsigned)f2b(hn)) << (16 * u);
                }
                cst_u32((unsigned*)&p.hbf[b * H + tid * 2], hpack);
                *(unsigned*)&p.hallb[((size_t)t * BB + b) * H + tid * 2] = hpack;
                if (last) {
#pragma unroll
                    for (int u = 0; u < 2; ++u) {
                        p.out_h[b * H + tid * 2 + u] = hn2[u];
                        p.out_c[b * H + tid * 2 + u] = cn2[u];
                    }
                }
            }
            __syncthreads();   // drain h stores
            if (tid < 8)       // publish h-done to all 8 replicas
                __hip_atomic_store(&p.hflag[(tid * 128 + beta) * 32], st,
                                   __ATOMIC_RELAXED, __HIP_MEMORY_SCOPE_AGENT);
        }
    }
}

// ---------------------------------------------------------------------------
// In-place log-softmax over each row of 5000 logits.
// ---------------------------------------------------------------------------
__global__ __launch_bounds__(256)
void logsoftmax_rows(float* __restrict__ P)
{
    __shared__ float red[256];
    float* p = P + (size_t)blockIdx.x * V;
    const int tid = threadIdx.x;
    float m = -1e30f;
    for (int i = tid; i < V; i += 256) m = fmaxf(m, p[i]);
    red[tid] = m; __syncthreads();
    for (int sft = 128; sft; sft >>= 1) {
        if (tid < sft) red[tid] = fmaxf(red[tid], red[tid + sft]);
        __syncthreads();
    }
    m = red[0]; __syncthreads();
    float ssum = 0.f;
    for (int i = tid; i < V; i += 256) ssum += __expf(p[i] - m);
    red[tid] = ssum; __syncthreads();
    for (int sft = 128; sft; sft >>= 1) {
        if (tid < sft) red[tid] += red[tid + sft];
        __syncthreads();
    }
    const float lse = m + __logf(red[0]);
    for (int i = tid; i < V; i += 256) p[i] -= lse;
}

// ---------------------------------------------------------------------------
extern "C" void kernel_launch(void* const* d_in, const int* in_sizes, int n_in,
                              void* d_out, int out_size, void* d_ws, size_t ws_size,
                              hipStream_t stream)
{
    (void)in_sizes; (void)n_in; (void)out_size; (void)ws_size;
    const float* enc  = (const float*)d_in[0];
    const float* h0   = (const float*)d_in[1];
    const float* c0   = (const float*)d_in[2];
    const int*   tgt  = (const int*)  d_in[3];
    const float* emb  = (const float*)d_in[4];
    const float* Wa   = (const float*)d_in[5];
    const float* ba   = (const float*)d_in[6];
    const float* Ua   = (const float*)d_in[7];
    const float* bu   = (const float*)d_in[8];
    const float* Va   = (const float*)d_in[9];
    const float* bv   = (const float*)d_in[10];
    const float* Wih  = (const float*)d_in[11];
    const float* Whh  = (const float*)d_in[12];
    const float* bih  = (const float*)d_in[13];
    const float* bhh  = (const float*)d_in[14];
    const float* Wout = (const float*)d_in[15];
    const float* bout = (const float*)d_in[16];

    float* ws = (float*)d_ws;
    float* Y    = ws;                                      // 327,680 f32
    float* bbig = Y + 327680;                              // 2,560 f32
    unsigned* flags = (unsigned*)(bbig + 2560);            // 78,848 u32 total
    unsigned* pflag    = flags;                            // 5,120
    unsigned* qaflag   = flags + 5120;                     // 8,192  (8x32x32)
    unsigned* gateflag = flags + 13312;                    // 32,768 (8x128x32)
    unsigned* hflag    = flags + 46080;                    // 32,768 (8x128x32)
    unsigned short* Wbig  = (unsigned short*)(flags + 78848);  // 2,621,440 u16
    unsigned short* Wc    = Wbig + 2621440;                // 1,048,576
    unsigned short* Uab   = Wc + 1048576;                  // 262,144
    unsigned short* Woutb = Uab + 262144;                  // 2,560,000
    unsigned short* encb  = Woutb + 2560000;               // 4,194,304
    unsigned short* keysb = encb + 4194304;                // 4,194,304
    unsigned short* xall  = keysb + 4194304;               // 3,407,872
    unsigned short* hallb = xall + 3407872;                // 3,407,872
    unsigned short* hbf   = hallb + 3407872;               // 65,536
    unsigned char*  encW8 = (unsigned char*)(hbf + 65536); // 16,777,216 u8

    float* out    = (float*)d_out;
    float* out_h  = out + (size_t)BB * TT * V;
    float* out_c  = out_h + BB * H;
    float* out_at = out_c + BB * H;

    hipMemsetAsync(flags, 0, 78848 * sizeof(unsigned), stream);

    prep_w<<<dim3(2048), dim3(256), 0, stream>>>(
        Wa, Whh, Wih, ba, bih, bhh, Ua, Wout, enc, Wbig, Wc, Uab, Woutb, encb, bbig);
    gather_x<<<dim3(512), dim3(256), 0, stream>>>(emb, tgt, xall);

    // keys_proj = enc @ Ua^T + bu  -> bf16 [8192,512]
    gemm_mfma<1, 0><<<dim3(4, 64), dim3(256), 0, stream>>>(
        encb, Uab, bu, nullptr, keysb, nullptr, BB * SS, H);
    // encW8 = enc @ Wc^T -> fp8 [8192,2048]  (L2-resident per-XCD slices)
    gemm_mfma<2, 0><<<dim3(16, 64), dim3(256), 0, stream>>>(
        encb, Wc, nullptr, nullptr, nullptr, encW8, BB * SS, 2048);

    PParams pp;
    pp.h0 = h0; pp.c0 = c0; pp.keysb = keysb; pp.encW8 = encW8;
    pp.Va = Va; pp.bv = bv; pp.bbig = bbig;
    pp.Wbig = Wbig; pp.xall = xall;
    pp.hbf = hbf; pp.Y = Y; pp.hallb = hallb;
    pp.attn = out_at; pp.out_h = out_h; pp.out_c = out_c;
    pp.pflag = pflag; pp.qaflag = qaflag; pp.gateflag = gateflag; pp.hflag = hflag;
    persist<<<dim3(NB), dim3(256), 0, stream>>>(pp);

    // logits: hallb[6656,512] @ Woutb^T + bout -> out[b,t,:], then log-softmax
    gemm_mfma<0, 1><<<dim3(40, 52), dim3(256), 0, stream>>>(
        hallb, Woutb, bout, out, nullptr, nullptr, TT * BB, V);
    logsoftmax_rows<<<dim3(BB * TT), dim3(256), 0, stream>>>(out);
}